// Round 11
// baseline (150.851 us; speedup 1.0000x reference)
//
#include <hip/hip_runtime.h>
#include <hip/hip_bf16.h>
#include <math.h>

#define B_ 8
#define N_ 512
#define K_ 128
#define M_ 100
#define NPAIR (B_*N_)    // 4096
#define DRLEN 1600
#define F0 240
#define NPAD 256

#define NLUT 2048
#define LUT2_STRIDE 128      // float2 per row (100 used)
#define SMAX 1.5f
#define EPB 8                // LUT entries per block

using bf16x8 = __attribute__((ext_vector_type(8))) __bf16;
using f32x4  = __attribute__((ext_vector_type(4))) float;

static __device__ __forceinline__ float tanh_f(float x){
  float xc = fminf(fmaxf(x, -15.f), 15.f);
  float e = __expf(2.f*xc);
  return __fdividef(e - 1.f, e + 1.f);
}

static __device__ __forceinline__ __bf16 f2b(float v){
  __hip_bfloat16 h = __float2bfloat16(v);
  return *reinterpret_cast<__bf16*>(&h);
}

// ---------------------------------------------------------------------------
// Fused prep: W0 transpose | W1T/W2T/biases/w3p/b3s/out-zero | LUT build.
// ---------------------------------------------------------------------------
#define W0T_BLOCKS 100                                 // 25 x 4 tiles
#define N2 (2*NPAD*NPAD)                               // 131072
#define SMALL_ELEMS (N2 + 4*NPAD + 9)                  // + b0,b1,b2,w3p + b3s + out[8]
#define SMALL_BLOCKS ((SMALL_ELEMS + 255)/256)
#define LUT_BLOCKS (NLUT/EPB)                          // 256

__global__ __launch_bounds__(256) void prep_fused(
    const float* __restrict__ fw0, const float* __restrict__ fw1,
    const float* __restrict__ fw2, const float* __restrict__ fw3,
    const float* __restrict__ fb0, const float* __restrict__ fb1,
    const float* __restrict__ fb2, const float* __restrict__ fb3,
    const float* __restrict__ ew0, const float* __restrict__ eb0,
    const float* __restrict__ ew1, const float* __restrict__ eb1,
    const float* __restrict__ ew2, const float* __restrict__ eb2,
    __hip_bfloat16* __restrict__ W0T, __hip_bfloat16* __restrict__ W1T,
    __hip_bfloat16* __restrict__ W2T,
    float* __restrict__ b0p, float* __restrict__ b1p, float* __restrict__ b2p,
    float* __restrict__ w3p, float* __restrict__ b3s,
    float* __restrict__ out, float2* __restrict__ T2)
{
  __shared__ float tile[64][65];
  __shared__ float sh0[EPB][26];
  __shared__ float sh1[EPB][52];
  const int bb = blockIdx.x;
  const int t = threadIdx.x;

  if (bb < W0T_BLOCKS){
    const int k0 = (bb % 25) * 64;
    const int n0 = (bb / 25) * 64;
    const int tc = t & 63, tr = t >> 6;
    #pragma unroll
    for (int i = 0; i < 16; i++){
      int r = i*4 + tr;
      int n = n0 + tc;
      tile[r][tc] = (n < F0) ? fw0[(size_t)(k0 + r)*F0 + n] : 0.f;
    }
    __syncthreads();
    #pragma unroll
    for (int i = 0; i < 16; i++){
      int r = i*4 + tr;
      W0T[(size_t)(n0 + r)*DRLEN + k0 + tc] = __float2bfloat16(tile[tc][r]);
    }
  } else if (bb < W0T_BLOCKS + SMALL_BLOCKS){
    int idx = (bb - W0T_BLOCKS)*256 + t;
    if (idx < NPAD*NPAD){
      int n = idx / NPAD, k = idx % NPAD;
      W1T[idx] = __float2bfloat16((n < F0 && k < F0) ? fw1[(size_t)k*F0 + n] : 0.f);
    } else if (idx < N2){
      int j = idx - NPAD*NPAD;
      int n = j / NPAD, k = j % NPAD;
      W2T[j] = __float2bfloat16((n < F0 && k < F0) ? fw2[(size_t)k*F0 + n] : 0.f);
    } else if (idx < N2 + NPAD){
      int c = idx - N2;            b0p[c] = (c < F0) ? fb0[c] : 0.f;
    } else if (idx < N2 + 2*NPAD){
      int c = idx - N2 - NPAD;     b1p[c] = (c < F0) ? fb1[c] : 0.f;
    } else if (idx < N2 + 3*NPAD){
      int c = idx - N2 - 2*NPAD;   b2p[c] = (c < F0) ? fb2[c] : 0.f;
    } else if (idx < N2 + 4*NPAD){
      int c = idx - N2 - 3*NPAD;   w3p[c] = (c < F0) ? fw3[c] : 0.f;
    } else if (idx == N2 + 4*NPAD){
      b3s[0] = fb3[0];
    } else if (idx < N2 + 4*NPAD + 9){
      out[idx - (N2 + 4*NPAD + 1)] = 0.f;     // zero Etot accumulators
    }
  } else {
    const int e0 = (bb - W0T_BLOCKS - SMALL_BLOCKS) * EPB;
    if (t < EPB*25){
      int e = t / 25, c = t % 25;
      float S = (float)(e0 + e) * (SMAX / (float)(NLUT - 1));
      sh0[e][c] = tanh_f(fmaf(S, ew0[c], eb0[c]));
    }
    __syncthreads();
    for (int o = t; o < EPB*50; o += 256){
      int e = o / 50, c = o % 50;
      float a = eb1[c], b = 0.f;
      #pragma unroll
      for (int k = 0; k < 24; k += 2){
        a = fmaf(sh0[e][k],   ew1[k*50 + c],     a);
        b = fmaf(sh0[e][k+1], ew1[(k+1)*50 + c], b);
      }
      a = fmaf(sh0[e][24], ew1[24*50 + c], a);
      sh1[e][c] = tanh_f(a + b);
    }
    __syncthreads();
    for (int o = t; o < EPB*M_; o += 256){
      int e = o / M_, c = o % M_;
      float a = eb2[c], b = 0.f;
      #pragma unroll
      for (int k = 0; k < 50; k += 2){
        a = fmaf(sh1[e][k],   ew2[k*M_ + c],     a);
        b = fmaf(sh1[e][k+1], ew2[(k+1)*M_ + c], b);
      }
      float g = tanh_f(a + b);
      int ge = e0 + e;
      T2[(size_t)ge*LUT2_STRIDE + c].x = g;
      if (ge > 0)
        T2[(size_t)(ge-1)*LUT2_STRIDE + c].y = g;
    }
  }
}

// ---------------------------------------------------------------------------
// Embed: per (b,n) pair. ALL 128 j (no prefix skip — r9 bug). 8-way unroll,
// split accumulators.
// ---------------------------------------------------------------------------
__global__ __launch_bounds__(128) void embed_kernel(
    const float* __restrict__ img, const float2* __restrict__ T2,
    __hip_bfloat16* __restrict__ DR)
{
  __shared__ float4 sRi[K_];
  __shared__ int    sJ[K_];
  __shared__ float  sW[K_];
  __shared__ float  sB[4][M_];

  const int pair = blockIdx.x;
  const int t = threadIdx.x;

  {
    float4 v = *(const float4*)(img + ((size_t)pair*K_ + t)*4);
    float x = v.x, y = v.y, z = v.z, fl = v.w;
    float R = fmaf(x, x, fmaf(y, y, z*z));
    bool mask = fl > 0.f;
    bool lt10 = R < 10.f;
    float safe = (R == 0.f) ? 1.f : R;
    float Sc = 0.5f*cosf(0.20943951023931953f*(R - 10.f)) + 0.5f;
    float S;
    if (mask && lt10)            S = 1.f/safe;
    else if (!lt10 && R < 25.f)  S = Sc;
    else                         S = 0.f;
    float coef = mask ? S/safe : 0.f;
    sRi[t] = make_float4(S, coef*x, coef*y, coef*z);

    float fidx = fminf(S, SMAX) * ((float)(NLUT - 1) / SMAX);
    float fi = floorf(fidx);
    int i = (int)fi;
    float w = fidx - fi;
    if (i > NLUT - 2){ i = NLUT - 2; w = 1.f; }
    sJ[t] = i * LUT2_STRIDE;
    sW[t] = w;
  }
  __syncthreads();

  if (t < M_){
    const int m = t;
    float a0[4] = {0.f,0.f,0.f,0.f};
    float a1[4] = {0.f,0.f,0.f,0.f};
    for (int j = 0; j < K_; j += 8){
      float2 tv[8];
      #pragma unroll
      for (int u = 0; u < 8; u++) tv[u] = T2[sJ[j+u] + m];
      #pragma unroll
      for (int u = 0; u < 8; u++){
        float g = fmaf(sW[j+u], tv[u].y - tv[u].x, tv[u].x);
        float4 ri = sRi[j+u];
        if ((u & 1) == 0){
          a0[0] = fmaf(ri.x, g, a0[0]);
          a0[1] = fmaf(ri.y, g, a0[1]);
          a0[2] = fmaf(ri.z, g, a0[2]);
          a0[3] = fmaf(ri.w, g, a0[3]);
        } else {
          a1[0] = fmaf(ri.x, g, a1[0]);
          a1[1] = fmaf(ri.y, g, a1[1]);
          a1[2] = fmaf(ri.z, g, a1[2]);
          a1[3] = fmaf(ri.w, g, a1[3]);
        }
      }
    }
    sB[0][m] = a0[0] + a1[0];
    sB[1][m] = a0[1] + a1[1];
    sB[2][m] = a0[2] + a1[2];
    sB[3][m] = a0[3] + a1[3];
  }
  __syncthreads();

  __hip_bfloat16* drp = DR + (size_t)pair*DRLEN;
  for (int o = t; o < DRLEN; o += 128){
    int m = o / M_, h = o % M_;
    float d = sB[0][m]*sB[0][h] + sB[1][m]*sB[1][h]
            + sB[2][m]*sB[2][h] + sB[3][m]*sB[3][h];
    drp[o] = __float2bfloat16(d);
  }
}

// ---------------------------------------------------------------------------
// LDS double-buffered MFMA GEMM (layer 0 only): H1 = tanh(DR @ W0T^T + b0).
// BM=BN=BK=64, 4 waves 2x2, wave tile 32x32, fully unrolled.
// ---------------------------------------------------------------------------
template<int KK, int NITER>
__global__ __launch_bounds__(256) void gemm_lds(
    const __hip_bfloat16* __restrict__ A_, const __hip_bfloat16* __restrict__ Bt_,
    const float* __restrict__ bias, __hip_bfloat16* __restrict__ Y)
{
  __shared__ __align__(16) __bf16 As[2][64][72];
  __shared__ __align__(16) __bf16 Bs[2][64][72];

  const __bf16* A  = (const __bf16*)A_;
  const __bf16* Bt = (const __bf16*)Bt_;
  const int tid = threadIdx.x;
  const int lane = tid & 63, wave = tid >> 6;
  const int wm = wave & 1, wn = wave >> 1;
  const int l15 = lane & 15, q = lane >> 4;
  const int row0 = blockIdx.x * 64;
  const int col0 = blockIdx.y * 64;

  int arow[2], ac8[2]; size_t aoff[2], boff[2];
  #pragma unroll
  for (int i = 0; i < 2; i++){
    int cid = tid + i*256; arow[i] = cid >> 3; ac8[i] = cid & 7;
    aoff[i] = (size_t)(row0 + arow[i])*KK + ac8[i]*8;
    boff[i] = (size_t)(col0 + arow[i])*KK + ac8[i]*8;
  }

  bf16x8 Ar[2][2], Br[2][2];

  #pragma unroll
  for (int i = 0; i < 2; i++) Ar[0][i] = *(const bf16x8*)(A + aoff[i]);
  #pragma unroll
  for (int i = 0; i < 2; i++) Br[0][i] = *(const bf16x8*)(Bt + boff[i]);
  #pragma unroll
  for (int i = 0; i < 2; i++) *(bf16x8*)&As[0][arow[i]][ac8[i]*8] = Ar[0][i];
  #pragma unroll
  for (int i = 0; i < 2; i++) *(bf16x8*)&Bs[0][arow[i]][ac8[i]*8] = Br[0][i];
  #pragma unroll
  for (int i = 0; i < 2; i++) Ar[1][i] = *(const bf16x8*)(A + aoff[i] + 64);
  #pragma unroll
  for (int i = 0; i < 2; i++) Br[1][i] = *(const bf16x8*)(Bt + boff[i] + 64);
  __syncthreads();

  f32x4 acc[2][2] = {};

  #pragma unroll
  for (int it = 0; it < NITER; it++){
    const int buf = it & 1;
    #pragma unroll
    for (int ks = 0; ks < 2; ks++){
      bf16x8 a0 = *(const bf16x8*)&As[buf][wm*32 +      l15][ks*32 + q*8];
      bf16x8 a1 = *(const bf16x8*)&As[buf][wm*32 + 16 + l15][ks*32 + q*8];
      bf16x8 b0 = *(const bf16x8*)&Bs[buf][wn*32 +      l15][ks*32 + q*8];
      bf16x8 b1 = *(const bf16x8*)&Bs[buf][wn*32 + 16 + l15][ks*32 + q*8];
      acc[0][0] = __builtin_amdgcn_mfma_f32_16x16x32_bf16(a0, b0, acc[0][0], 0,0,0);
      acc[1][0] = __builtin_amdgcn_mfma_f32_16x16x32_bf16(a1, b0, acc[1][0], 0,0,0);
      acc[0][1] = __builtin_amdgcn_mfma_f32_16x16x32_bf16(a0, b1, acc[0][1], 0,0,0);
      acc[1][1] = __builtin_amdgcn_mfma_f32_16x16x32_bf16(a1, b1, acc[1][1], 0,0,0);
    }
    if (it + 1 < NITER){
      const int nb = buf ^ 1;
      const int set = (it + 1) & 1;
      #pragma unroll
      for (int i = 0; i < 2; i++) *(bf16x8*)&As[nb][arow[i]][ac8[i]*8] = Ar[set][i];
      #pragma unroll
      for (int i = 0; i < 2; i++) *(bf16x8*)&Bs[nb][arow[i]][ac8[i]*8] = Br[set][i];
      if (it + 2 < NITER){
        const int s2 = it & 1;
        const size_t k2 = (size_t)(it + 2) * 64;
        #pragma unroll
        for (int i = 0; i < 2; i++) Ar[s2][i] = *(const bf16x8*)(A + aoff[i] + k2);
        #pragma unroll
        for (int i = 0; i < 2; i++) Br[s2][i] = *(const bf16x8*)(Bt + boff[i] + k2);
      }
      __syncthreads();
    }
  }

  #pragma unroll
  for (int i = 0; i < 2; i++){
    #pragma unroll
    for (int j = 0; j < 2; j++){
      int c = col0 + wn*32 + j*16 + l15;
      float bs = bias[c];
      #pragma unroll
      for (int r = 0; r < 4; r++){
        int rr = row0 + wm*32 + i*16 + q*4 + r;
        float v = tanh_f(acc[i][j][r] + bs);
        Y[(size_t)rr*NPAD + c] = __float2bfloat16(v);
      }
    }
  }
}

// ---------------------------------------------------------------------------
// fit23: fused layers 2+3 + GEMV + Etot.  Block = 16 rows x 256 thr (4 waves,
// wave w owns cols w*64..+63).  H1 tile staged once; W k-slices double-
// buffered; H2 lives only in LDS; Ei -> out[8..]; Etot via atomicAdd into
// out[0..7] (zeroed by prep_fused earlier in the stream).
// ---------------------------------------------------------------------------
__global__ __launch_bounds__(256) void fit23(
    const __hip_bfloat16* __restrict__ H1_,
    const __hip_bfloat16* __restrict__ W1T_, const __hip_bfloat16* __restrict__ W2T_,
    const float* __restrict__ b1p, const float* __restrict__ b2p,
    const float* __restrict__ w3p, const float* __restrict__ b3s,
    float* __restrict__ out)
{
  __shared__ __align__(16) __bf16 Hs[16][268];     // row stride 536B: conflict-free frags
  __shared__ __align__(16) __bf16 Bs[2][256][36];  // row stride 72B
  __shared__ float sEi[4][16];

  const __bf16* H1  = (const __bf16*)H1_;
  const int tid = threadIdx.x;
  const int lane = tid & 63, wave = tid >> 6;
  const int l15 = lane & 15, q = lane >> 4;
  const int r0 = blockIdx.x * 16;
  const int wc0 = wave * 64;

  // stage H1 rows (16 x 256 bf16)
  #pragma unroll
  for (int i = 0; i < 2; i++){
    int c = tid + i*256;            // 512 chunks of 8
    int row = c >> 5, c8 = c & 31;
    *(bf16x8*)&Hs[row][c8*8] = *(const bf16x8*)(H1 + (size_t)(r0 + row)*NPAD + c8*8);
  }

  auto stageB = [&](const __bf16* Bt, int k0, int buf){
    #pragma unroll
    for (int i = 0; i < 4; i++){
      int c = tid + i*256;          // 1024 chunks of 8 (256 n x 32 k)
      int n = c >> 2, k8 = c & 3;
      *(bf16x8*)&Bs[buf][n][k8*8] = *(const bf16x8*)(Bt + (size_t)n*NPAD + k0 + k8*8);
    }
  };

  for (int layer = 0; layer < 2; layer++){
    const __bf16* Bt  = (layer == 0) ? (const __bf16*)W1T_ : (const __bf16*)W2T_;
    const float* bias = (layer == 0) ? b1p : b2p;

    f32x4 acc[4] = {};
    stageB(Bt, 0, 0);
    __syncthreads();                 // Bs[0] ready; Hs writes (load or H2) done

    for (int it = 0; it < 8; it++){
      const int buf = it & 1;
      const int k0 = it * 32;
      bf16x8 a = *(const bf16x8*)&Hs[l15][k0 + q*8];
      #pragma unroll
      for (int tnum = 0; tnum < 4; tnum++){
        bf16x8 b = *(const bf16x8*)&Bs[buf][wc0 + tnum*16 + l15][q*8];
        acc[tnum] = __builtin_amdgcn_mfma_f32_16x16x32_bf16(a, b, acc[tnum], 0,0,0);
      }
      if (it + 1 < 8) stageB(Bt, (it+1)*32, buf ^ 1);
      __syncthreads();
    }

    if (layer == 0){
      // H2 = tanh(acc + b1) -> back into Hs (all Hs reads finished above)
      #pragma unroll
      for (int tnum = 0; tnum < 4; tnum++){
        int col = wc0 + tnum*16 + l15;
        float bs = bias[col];
        #pragma unroll
        for (int r = 0; r < 4; r++)
          Hs[q*4 + r][col] = f2b(tanh_f(acc[tnum][r] + bs));
      }
      __syncthreads();
    } else {
      // H3 + GEMV partials over this wave's 64 cols
      float part[4] = {0.f,0.f,0.f,0.f};
      #pragma unroll
      for (int tnum = 0; tnum < 4; tnum++){
        int col = wc0 + tnum*16 + l15;
        float bs = bias[col];
        float wv = w3p[col];
        #pragma unroll
        for (int r = 0; r < 4; r++){
          float h = tanh_f(acc[tnum][r] + bs);
          part[r] = fmaf(h, wv, part[r]);
        }
      }
      #pragma unroll
      for (int off = 1; off < 16; off <<= 1){
        #pragma unroll
        for (int r = 0; r < 4; r++) part[r] += __shfl_xor(part[r], off, 64);
      }
      if (l15 == 0){
        #pragma unroll
        for (int r = 0; r < 4; r++) sEi[wave][q*4 + r] = part[r];
      }
      __syncthreads();
      if (tid < 16){
        float e = sEi[0][tid] + sEi[1][tid] + sEi[2][tid] + sEi[3][tid] + b3s[0];
        out[8 + r0 + tid] = e;
        float v = e;
        #pragma unroll
        for (int off = 1; off < 16; off <<= 1) v += __shfl_xor(v, off, 64);
        if (tid == 0) atomicAdd(&out[r0 >> 9], v);
      }
    }
  }
}

extern "C" void kernel_launch(void* const* d_in, const int* in_sizes, int n_in,
                              void* d_out, int out_size, void* d_ws, size_t ws_size,
                              hipStream_t stream)
{
  const float* img = (const float*)d_in[0];
  const float* ew0 = (const float*)d_in[1];
  const float* eb0 = (const float*)d_in[2];
  const float* ew1 = (const float*)d_in[3];
  const float* eb1 = (const float*)d_in[4];
  const float* ew2 = (const float*)d_in[5];
  const float* eb2 = (const float*)d_in[6];
  const float* fw0 = (const float*)d_in[7];
  const float* fb0 = (const float*)d_in[8];
  const float* fw1 = (const float*)d_in[9];
  const float* fb1 = (const float*)d_in[10];
  const float* fw2 = (const float*)d_in[11];
  const float* fb2 = (const float*)d_in[12];
  const float* fw3 = (const float*)d_in[13];
  const float* fb3 = (const float*)d_in[14];

  char* w = (char*)d_ws;
  __hip_bfloat16* DRb = (__hip_bfloat16*)(w);                 // 13107200 B
  __hip_bfloat16* H1b = (__hip_bfloat16*)(w + 13107200);      // 2097152 B
  __hip_bfloat16* W0T = (__hip_bfloat16*)(w + 15204352);      // 819200 B
  __hip_bfloat16* W1T = (__hip_bfloat16*)(w + 16023552);      // 131072 B
  __hip_bfloat16* W2T = (__hip_bfloat16*)(w + 16154624);      // 131072 B
  float* b0p = (float*)(w + 16285696);                        // 1024 B each
  float* b1p = (float*)(w + 16286720);
  float* b2p = (float*)(w + 16287744);
  float* w3p = (float*)(w + 16288768);
  float* b3s = (float*)(w + 16289792);
  float2* LUT2 = (float2*)(w + 16290816);                     // 2097152 B

  float* out = (float*)d_out;                                 // [0..7]=Etot, [8..]=Ei

  prep_fused<<<W0T_BLOCKS + SMALL_BLOCKS + LUT_BLOCKS, 256, 0, stream>>>(
      fw0, fw1, fw2, fw3, fb0, fb1, fb2, fb3,
      ew0, eb0, ew1, eb1, ew2, eb2,
      W0T, W1T, W2T, b0p, b1p, b2p, w3p, b3s, out, LUT2);

  embed_kernel<<<NPAIR, 128, 0, stream>>>(img, LUT2, DRb);

  dim3 gg(NPAIR/64, NPAD/64);
  gemm_lds<DRLEN, 25><<<gg, 256, 0, stream>>>(DRb, W0T, b0p, H1b);

  fit23<<<NPAIR/16, 256, 0, stream>>>(H1b, W1T, W2T, b1p, b2p, w3p, b3s, out);
}